// Round 2
// baseline (352.404 us; speedup 1.0000x reference)
//
#include <hip/hip_runtime.h>

#define N_THRESH 100
#define NBINS 101
#define TPB 384           // 6 waves/block; LDS (152 KB) caps at 1 block/CU
#define GRID 1024         // 4 serial block-rounds/CU: scheduler self-balances
#define FLUSH_GROUPS 29   // 29*8=232 +remainder(<=8) <= 252: u8 fields safe (never hit at n=2^25)

// ---------------------------------------------------------------------------
// Kernel 0: zero accumulator bins + completion ticket (d_ws poisoned 0xAA).
// ---------------------------------------------------------------------------
__global__ void zero_ws_kernel(unsigned long long* __restrict__ ws) {
    int i = threadIdx.x;
    if (i < NBINS + 1) ws[i] = 0ull;   // [0..100] = (pos<<32|cnt), [101] = ticket
}

// ---------------------------------------------------------------------------
// Branch-free exact bin: cnt = searchsorted(thresholds, v, side='left'),
// thresholds[k] = float32(double(k)*0.01) (bit-exact np.arange match).
// Verified absmax=0 across two sessions — do not touch.
// ---------------------------------------------------------------------------
__device__ __forceinline__ int bin_of(float v) {
    int e = (int)(v * 100.0f);
    e = e < 0 ? 0 : (e > 99 ? 99 : e);
    double ed = (double)e * 0.01;
    float t0 = (float)ed;           // threshold e
    float t1 = (float)(ed + 0.01);  // threshold e+1 (==1.0f when e==99)
    int c = e + (t0 < v ? 1 : 0) + (t1 < v ? 1 : 0);
    return c > N_THRESH ? N_THRESH : c;
}

// Per-thread private cell in the given array: u16 = (pos<<8)|cnt, fields <= 252
// between flushes -> no cross-byte carry. Plain RMW, no atomics.
__device__ __forceinline__ void bump(unsigned short* h, int tid, float v, int g) {
    h[bin_of(v) * TPB + tid] += (unsigned short)(1u + (g != 0 ? 256u : 0u));
}

// Fold one bin-row (TPB u16 cells = TPB/2 dwords) into acc. Stagger start by r:
// dword index = r*192 + (j+r)%192 -> bank (193r+j)&31 = (r+j)&31 -> 2 lanes/bank.
__device__ __forceinline__ void fold_row(const unsigned short* h, int r,
                                         unsigned long long& acc_c,
                                         unsigned long long& acc_p) {
    const unsigned int* row = (const unsigned int*)(h + r * TPB);
    unsigned int c = 0, p = 0;
    for (int j = 0; j < TPB / 2; ++j) {
        int jj = j + r; if (jj >= TPB / 2) jj -= TPB / 2;
        unsigned int v = row[jj];
        c += (v & 0xffu) + ((v >> 16) & 0xffu);
        p += ((v >> 8) & 0xffu) + ((v >> 24) & 0xffu);
    }
    acc_c += c; acc_p += p;
}

// Alternate elements sA/sB: two independent RMW chains the compiler CAN
// interleave (distinct __shared__ objects -> no alias) -> 2x chain ILP.
#define PROCESS16(PA, PB, PC, PD, GA, GB, GC, GD) do {            \
    bump(sA, tid, (PA).x, (GA).x); bump(sB, tid, (PA).y, (GA).y); \
    bump(sA, tid, (PA).z, (GA).z); bump(sB, tid, (PA).w, (GA).w); \
    bump(sA, tid, (PB).x, (GB).x); bump(sB, tid, (PB).y, (GB).y); \
    bump(sA, tid, (PB).z, (GB).z); bump(sB, tid, (PB).w, (GB).w); \
    bump(sA, tid, (PC).x, (GC).x); bump(sB, tid, (PC).y, (GC).y); \
    bump(sA, tid, (PC).z, (GC).z); bump(sB, tid, (PC).w, (GC).w); \
    bump(sA, tid, (PD).x, (GD).x); bump(sB, tid, (PD).y, (GD).y); \
    bump(sA, tid, (PD).z, (GD).z); bump(sB, tid, (PD).w, (GD).w); \
} while (0)

// ---------------------------------------------------------------------------
// Kernel 1: histogram + (last block) finalize. No separate finalize launch.
// ---------------------------------------------------------------------------
__global__ __launch_bounds__(TPB) void hist_kernel(
        const float* __restrict__ pred,
        const int* __restrict__ gt,
        unsigned long long* __restrict__ ws,
        float* __restrict__ out,
        int n) {
    __shared__ unsigned short sA[NBINS * TPB];   // 77,568 B
    __shared__ unsigned short sB[NBINS * TPB];   // 77,568 B
    __shared__ unsigned int fpos[NBINS], fall[NBINS];
    __shared__ int is_last;

    const int tid = threadIdx.x;
    unsigned int* const za = (unsigned int*)sA;
    unsigned int* const zb = (unsigned int*)sB;

    for (int i = tid; i < NBINS * (TPB / 2); i += TPB) { za[i] = 0u; zb[i] = 0u; }
    __syncthreads();

    const int nvec = n >> 2;
    const float4* __restrict__ p4 = (const float4*)pred;
    const int4*   __restrict__ g4 = (const int4*)gt;
    const int gsz = gridDim.x * blockDim.x;
    const int i0  = blockIdx.x * blockDim.x + tid;
    const int iters  = nvec / gsz;   // uniform: every thread has >= iters vec4s
    const int groups = iters >> 2;   // 16-element groups, uniform across grid

    unsigned long long acc_c = 0ull, acc_p = 0ull;  // flush carry (role-local)

    int gs = 0;
    while (gs < groups) {
        const int ge = (groups < gs + FLUSH_GROUPS) ? groups : gs + FLUSH_GROUPS;
        // software-pipelined: group g+1's 8x16B loads issue BEFORE group g's
        // RMW chain -> ~900cy HBM latency hides under the ~1000cy chain.
        int j = i0 + gs * 4 * gsz;
        float4 pa = p4[j], pb = p4[j + gsz], pc = p4[j + 2 * gsz], pd = p4[j + 3 * gsz];
        int4   ga = g4[j], gb = g4[j + gsz], gc = g4[j + 2 * gsz], gd = g4[j + 3 * gsz];
        for (int g = gs + 1; g < ge; ++g) {
            j = i0 + g * 4 * gsz;
            float4 qa = p4[j], qb = p4[j + gsz], qc = p4[j + 2 * gsz], qd = p4[j + 3 * gsz];
            int4   ra = g4[j], rb = g4[j + gsz], rc = g4[j + 2 * gsz], rd = g4[j + 3 * gsz];
            PROCESS16(pa, pb, pc, pd, ga, gb, gc, gd);
            pa = qa; pb = qb; pc = qc; pd = qd;
            ga = ra; gb = rb; gc = rc; gd = rd;
        }
        PROCESS16(pa, pb, pc, pd, ga, gb, gc, gd);
        gs = ge;
        if (gs < groups) {
            // mid flush (generality guard; never runs at n=2^25)
            __syncthreads();
            if (tid < NBINS)                            fold_row(sA, tid, acc_c, acc_p);
            else if (tid >= 192 && tid < 192 + NBINS)   fold_row(sB, tid - 192, acc_c, acc_p);
            __syncthreads();
            for (int i = tid; i < NBINS * (TPB / 2); i += TPB) { za[i] = 0u; zb[i] = 0u; }
            __syncthreads();
        }
    }

    // per-thread remainder vec4s (non-uniform; <= 4 per thread)
    for (int k = groups * 4; ; ++k) {
        int i = i0 + k * gsz;
        if (i >= nvec) break;
        float4 p = p4[i]; int4 g = g4[i];
        bump(sA, tid, p.x, g.x); bump(sB, tid, p.y, g.y);
        bump(sA, tid, p.z, g.z); bump(sB, tid, p.w, g.w);
    }

    // scalar tail (n % 4) — empty at n=2^25
    if (blockIdx.x == 0 && tid == 0) {
        for (int k = nvec << 2; k < n; ++k) {
            int b = bin_of(pred[k]);
            sA[b * TPB] = (unsigned short)(sA[b * TPB] + 1u + (gt[k] != 0 ? 256u : 0u));
        }
    }

    __syncthreads();
    // fold B first into shared partials, then A combines -> ONE atomic/bin/block
    if (tid >= 192 && tid < 192 + NBINS) {
        fold_row(sB, tid - 192, acc_c, acc_p);
        fall[tid - 192] = (unsigned int)acc_c;
        fpos[tid - 192] = (unsigned int)acc_p;
    }
    __syncthreads();
    if (tid < NBINS) {
        fold_row(sA, tid, acc_c, acc_p);
        unsigned long long cnt = acc_c + fall[tid];
        unsigned long long pos = acc_p + fpos[tid];
        if (cnt | pos) atomicAdd(&ws[tid], (pos << 32) | cnt);
        __threadfence();   // make this block's adds device-visible before ticket
    }
    __syncthreads();
    if (tid == 0) {
        unsigned long long t = atomicAdd(&ws[NBINS], 1ull);
        is_last = (t == (unsigned long long)(gridDim.x - 1)) ? 1 : 0;
    }
    __syncthreads();

    if (is_last) {
        // ticket order + per-block fences guarantee all adds are visible;
        // atomic-read bypasses stale L1.
        if (tid < NBINS) {
            unsigned long long h = atomicAdd(&ws[tid], 0ull);
            fpos[tid] = (unsigned int)(h >> 32);
            fall[tid] = (unsigned int)(h & 0xffffffffull);
        }
        __syncthreads();
        if (tid < N_THRESH) {
            out[tid] = (float)((double)tid * 0.01);
            unsigned long long tp = 0, pp = 0, ngt = 0;
            for (int c = tid + 1; c <= N_THRESH; ++c) { tp += fpos[c]; pp += fall[c]; }
            for (int c = 0; c <= N_THRESH; ++c) ngt += fpos[c];
            long long uni = (long long)(pp + ngt - tp);   // TP + FP + FN
            double iou = (uni > 0) ? (double)tp / (double)uni : 0.0;
            out[N_THRESH + tid] = (float)iou;
        }
    }
}

// ---------------------------------------------------------------------------
extern "C" void kernel_launch(void* const* d_in, const int* in_sizes, int n_in,
                              void* d_out, int out_size, void* d_ws, size_t ws_size,
                              hipStream_t stream) {
    const float* pred = (const float*)d_in[0];
    const int*   gt   = (const int*)d_in[1];
    float* out = (float*)d_out;
    unsigned long long* ws = (unsigned long long*)d_ws;
    int n = in_sizes[0];

    zero_ws_kernel<<<1, 128, 0, stream>>>(ws);
    // GRID*TPB = 393,216 threads; per thread <= 22 vec4 -> <= 44 elems per
    // array column (u8 fields safe, no mid-flush). Finalize merged into the
    // last-finishing block via ws[101] ticket.
    hist_kernel<<<GRID, TPB, 0, stream>>>(pred, gt, ws, out, n);
}

// Round 6
// 295.545 us; speedup vs baseline: 1.1924x; 1.1924x over previous
//
#include <hip/hip_runtime.h>

#define N_THRESH 100
#define NBINS 101
#define TPB 256        // 4 waves/block; LDS 103,424 B -> 1 block/CU, 8 waves/CU
#define GRID 256       // one block per CU, single round

// ---------------------------------------------------------------------------
// Kernel 0: zero accumulator bins + completion ticket (d_ws poisoned 0xAA).
// ---------------------------------------------------------------------------
__global__ void zero_ws_kernel(unsigned long long* __restrict__ ws) {
    int i = threadIdx.x;
    if (i < NBINS + 1) ws[i] = 0ull;   // [0..100] = (pos<<32|cnt), [101] = ticket
}

// ---------------------------------------------------------------------------
// Branch-free exact bin: cnt = searchsorted(thresholds, v, side='left'),
// thresholds[k] = float32(double(k)*0.01) (bit-exact np.arange match).
// Verified absmax=0 across three runs — do not touch.
// ---------------------------------------------------------------------------
__device__ __forceinline__ int bin_of(float v) {
    int e = (int)(v * 100.0f);
    e = e < 0 ? 0 : (e > 99 ? 99 : e);
    double ed = (double)e * 0.01;
    float t0 = (float)ed;           // threshold e
    float t1 = (float)(ed + 0.01);  // threshold e+1 (==1.0f when e==99)
    int c = e + (t0 < v ? 1 : 0) + (t1 < v ? 1 : 0);
    return c > N_THRESH ? N_THRESH : c;
}

// Per-thread private u32 cell = (pos<<16)|cnt. Full-dword ds_read_b32/
// ds_write_b32 ONLY (u16 cells in v1/v2 measured ~67 cyc/wave-op ~ 1 cyc/lane
// with ~0 bank conflicts: sub-word scattered LDS is a per-lane slow path;
// conflict-free dword scatter should run at the m134 ~6 cyc rate).
// Max count per cell = 512 (<< 2^16): no overflow, no flush logic.
__device__ __forceinline__ void bump(unsigned int* __restrict__ h, int tid,
                                     float v, int g) {
    h[bin_of(v) * TPB + tid] += 1u + ((unsigned int)(g != 0) << 16);
}

#define PROCESS16(PA, PB, PC, PD, GA, GB, GC, GD) do {          \
    bump(h, tid, (PA).x, (GA).x); bump(h, tid, (PA).y, (GA).y); \
    bump(h, tid, (PA).z, (GA).z); bump(h, tid, (PA).w, (GA).w); \
    bump(h, tid, (PB).x, (GB).x); bump(h, tid, (PB).y, (GB).y); \
    bump(h, tid, (PB).z, (GB).z); bump(h, tid, (PB).w, (GB).w); \
    bump(h, tid, (PC).x, (GC).x); bump(h, tid, (PC).y, (GC).y); \
    bump(h, tid, (PC).z, (GC).z); bump(h, tid, (PC).w, (GC).w); \
    bump(h, tid, (PD).x, (GD).x); bump(h, tid, (PD).y, (GD).y); \
    bump(h, tid, (PD).z, (GD).z); bump(h, tid, (PD).w, (GD).w); \
} while (0)

// ---------------------------------------------------------------------------
// Kernel 1: histogram + (last block) finalize via ticket. No separate launch.
// Layout hist[bin][tid] u32: dword = bin*256+tid -> bank = tid&31 (256%32==0):
// deterministic 2 lanes/bank (free per m136), race-free (cell per thread).
// ---------------------------------------------------------------------------
__global__ __launch_bounds__(TPB) void hist_kernel(
        const float* __restrict__ pred,
        const int* __restrict__ gt,
        unsigned long long* __restrict__ ws,
        float* __restrict__ out,
        int n) {
    __shared__ unsigned int hist[NBINS][TPB];   // 103,424 B
    __shared__ unsigned int fpos[NBINS], fall[NBINS];
    __shared__ int is_last;

    const int tid = threadIdx.x;
    unsigned int* const h = &hist[0][0];

    for (int i = tid; i < NBINS * TPB; i += TPB) h[i] = 0u;   // bank=tid&31: conflict-free
    __syncthreads();

    const int nvec = n >> 2;
    const float4* __restrict__ p4 = (const float4*)pred;
    const int4*   __restrict__ g4 = (const int4*)gt;
    const int gsz = gridDim.x * blockDim.x;           // 65,536
    const int i0  = blockIdx.x * blockDim.x + tid;
    const int iters  = nvec / gsz;                    // 128 at n=2^25 (uniform)
    const int groups = iters >> 2;                    // 32

    int it = 0;
    if (groups > 0) {
        // software-pipelined: group g's 8x16B loads issue BEFORE group g-1's
        // RMW chain -> ~900cy HBM latency hides under the LDS chain; 8 waves
        // x 128B in flight per CU >> Little's-law need for full stream rate.
        int j = i0;
        float4 pa = p4[j], pb = p4[j + gsz], pc = p4[j + 2 * gsz], pd = p4[j + 3 * gsz];
        int4   ga = g4[j], gb = g4[j + gsz], gc = g4[j + 2 * gsz], gd = g4[j + 3 * gsz];
        for (int g = 1; g < groups; ++g) {
            j = i0 + g * 4 * gsz;
            float4 qa = p4[j], qb = p4[j + gsz], qc = p4[j + 2 * gsz], qd = p4[j + 3 * gsz];
            int4   ra = g4[j], rb = g4[j + gsz], rc = g4[j + 2 * gsz], rd = g4[j + 3 * gsz];
            PROCESS16(pa, pb, pc, pd, ga, gb, gc, gd);
            pa = qa; pb = qb; pc = qc; pd = qd;
            ga = ra; gb = rb; gc = rc; gd = rd;
        }
        PROCESS16(pa, pb, pc, pd, ga, gb, gc, gd);
        it = groups * 4;
    }
    for (; it < iters; ++it) {                        // remainder (0 at n=2^25)
        int i = i0 + it * gsz;
        float4 p = p4[i]; int4 g = g4[i];
        bump(h, tid, p.x, g.x); bump(h, tid, p.y, g.y);
        bump(h, tid, p.z, g.z); bump(h, tid, p.w, g.w);
    }
    {   // non-uniform extra vec4 (first nvec%gsz threads; none at n=2^25)
        int i = i0 + iters * gsz;
        if (i < nvec) {
            float4 p = p4[i]; int4 g = g4[i];
            bump(h, tid, p.x, g.x); bump(h, tid, p.y, g.y);
            bump(h, tid, p.z, g.z); bump(h, tid, p.w, g.w);
        }
    }

    // scalar tail (n % 4) — empty at n=2^25; tid 0's own column, race-free
    if (blockIdx.x == 0 && tid == 0) {
        for (int k = nvec << 2; k < n; ++k)
            h[bin_of(pred[k]) * TPB] += 1u + ((unsigned int)(gt[k] != 0) << 16);
    }

    __syncthreads();
    // fold: bin r sums its 256 u32 cells; staggered start ((j+tid)%256) keeps
    // reads <=4 lanes/bank. ONE global atomic per (block,bin): 256*101 total.
    if (tid < NBINS) {
        const unsigned int* row = &hist[tid][0];
        unsigned long long cnt = 0ull, pos = 0ull;
        for (int j = 0; j < TPB; ++j) {
            int jj = j + tid; if (jj >= TPB) jj -= TPB;
            unsigned int v = row[jj];
            cnt += v & 0xffffu;
            pos += v >> 16;
        }
        if (cnt | pos) atomicAdd(&ws[tid], (pos << 32) | cnt);
        __threadfence();   // adds device-visible before the ticket
    }
    __syncthreads();
    if (tid == 0) {
        unsigned long long t = atomicAdd(&ws[NBINS], 1ull);
        is_last = (t == (unsigned long long)(gridDim.x - 1)) ? 1 : 0;
    }
    __syncthreads();

    if (is_last) {
        if (tid < NBINS) {   // atomic-read: bypass stale L1, post-fence values
            unsigned long long hv = atomicAdd(&ws[tid], 0ull);
            fpos[tid] = (unsigned int)(hv >> 32);
            fall[tid] = (unsigned int)(hv & 0xffffffffull);
        }
        __syncthreads();
        if (tid < N_THRESH) {
            out[tid] = (float)((double)tid * 0.01);
            unsigned long long tp = 0, pp = 0, ngt = 0;
            for (int c = tid + 1; c <= N_THRESH; ++c) { tp += fpos[c]; pp += fall[c]; }
            for (int c = 0; c <= N_THRESH; ++c) ngt += fpos[c];
            long long uni = (long long)(pp + ngt - tp);   // TP + FP + FN
            double iou = (uni > 0) ? (double)tp / (double)uni : 0.0;
            out[N_THRESH + tid] = (float)iou;
        }
    }
}

// ---------------------------------------------------------------------------
extern "C" void kernel_launch(void* const* d_in, const int* in_sizes, int n_in,
                              void* d_out, int out_size, void* d_ws, size_t ws_size,
                              hipStream_t stream) {
    const float* pred = (const float*)d_in[0];
    const int*   gt   = (const int*)d_in[1];
    float* out = (float*)d_out;
    unsigned long long* ws = (unsigned long long*)d_ws;
    int n = in_sizes[0];

    zero_ws_kernel<<<1, 128, 0, stream>>>(ws);
    hist_kernel<<<GRID, TPB, 0, stream>>>(pred, gt, ws, out, n);
}

// Round 7
// 295.056 us; speedup vs baseline: 1.1944x; 1.0017x over previous
//
#include <hip/hip_runtime.h>

#define N_THRESH 100
#define NBINS 101
#define TPB 256        // 4 waves/block; LDS 103,424 B -> 1 block/CU, 8 waves/CU
#define GRID 256       // one block per CU, single round

// ---------------------------------------------------------------------------
// Kernel 0: zero accumulator bins + completion ticket (d_ws poisoned 0xAA).
// ---------------------------------------------------------------------------
__global__ void zero_ws_kernel(unsigned long long* __restrict__ ws) {
    int i = threadIdx.x;
    if (i < NBINS + 1) ws[i] = 0ull;   // [0..100] = (pos<<32|cnt), [101] = ticket
}

// ---------------------------------------------------------------------------
// Branch-free exact bin: cnt = searchsorted(thresholds, v, side='left'),
// thresholds[k] = float32(double(k)*0.01) (bit-exact np.arange match).
// Verified absmax=0 across four runs — do not touch.
// ---------------------------------------------------------------------------
__device__ __forceinline__ int bin_of(float v) {
    int e = (int)(v * 100.0f);
    e = e < 0 ? 0 : (e > 99 ? 99 : e);
    double ed = (double)e * 0.01;
    float t0 = (float)ed;           // threshold e
    float t1 = (float)(ed + 0.01);  // threshold e+1 (==1.0f when e==99)
    int c = e + (t0 < v ? 1 : 0) + (t1 < v ? 1 : 0);
    return c > N_THRESH ? N_THRESH : c;
}

// Per-thread private u32 cell = (pos<<16)|cnt, race-free, no atomics.
// R6 CONCLUSION: v0 (atomic, 2048 ops @135cy) == v1 (u16, 4096 @67) ==
// v4 (u32, 4096 @68) == ~277K cyc/CU. Either scattered-LDS runs ~1 cyc/lane
// (pipe saturated in all three) or HBM is pattern-limited at 1.15 TB/s.
// This version changes ONLY the global access pattern to discriminate.
__device__ __forceinline__ void bump(unsigned int* __restrict__ h, int tid,
                                     float v, int g) {
    h[bin_of(v) * TPB + tid] += 1u + ((unsigned int)(g != 0) << 16);
}

#define PROCESS16(PA, PB, PC, PD, GA, GB, GC, GD) do {          \
    bump(h, tid, (PA).x, (GA).x); bump(h, tid, (PA).y, (GA).y); \
    bump(h, tid, (PA).z, (GA).z); bump(h, tid, (PA).w, (GA).w); \
    bump(h, tid, (PB).x, (GB).x); bump(h, tid, (PB).y, (GB).y); \
    bump(h, tid, (PB).z, (GB).z); bump(h, tid, (PB).w, (GB).w); \
    bump(h, tid, (PC).x, (GC).x); bump(h, tid, (PC).y, (GC).y); \
    bump(h, tid, (PC).z, (GC).z); bump(h, tid, (PC).w, (GC).w); \
    bump(h, tid, (PD).x, (GD).x); bump(h, tid, (PD).y, (GD).y); \
    bump(h, tid, (PD).z, (GD).z); bump(h, tid, (PD).w, (GD).w); \
} while (0)

// ---------------------------------------------------------------------------
// Kernel 1: histogram + (last block) finalize via ticket.
// GLOBAL PATTERN CHANGE vs R6: block b owns ONE CONTIGUOUS slab of
// iters*TPB vec4s (1MB data) instead of 128 scattered 4KB slabs strided 1MB.
// Per-CU streams: 256 -> 8 (4 waves x 2 arrays). Wave coalescing unchanged
// (lane stride 16B within each 1KB wave segment).
// ---------------------------------------------------------------------------
__global__ __launch_bounds__(TPB) void hist_kernel(
        const float* __restrict__ pred,
        const int* __restrict__ gt,
        unsigned long long* __restrict__ ws,
        float* __restrict__ out,
        int n) {
    __shared__ unsigned int hist[NBINS][TPB];   // 103,424 B
    __shared__ unsigned int fpos[NBINS], fall[NBINS];
    __shared__ int is_last;

    const int tid = threadIdx.x;
    unsigned int* const h = &hist[0][0];

    for (int i = tid; i < NBINS * TPB; i += TPB) h[i] = 0u;   // bank=tid&31: conflict-free
    __syncthreads();

    const int nvec = n >> 2;
    const float4* __restrict__ p4 = (const float4*)pred;
    const int4*   __restrict__ g4 = (const int4*)gt;
    const int gsz   = gridDim.x * blockDim.x;         // 65,536
    const int iters = nvec / gsz;                     // 128 at n=2^25 (uniform)
    const int groups = iters >> 2;                    // 32
    // contiguous slab base for this block (vec4 units)
    const int base = blockIdx.x * (iters * TPB) + tid;

    int it = 0;
    if (groups > 0) {
        // software-pipelined: group g's 8x16B loads issue BEFORE group g-1's
        // RMW chain; 8KB/wave in flight >> 9.2KB/CU Little's-law need.
        int j = base;
        float4 pa = p4[j], pb = p4[j + TPB], pc = p4[j + 2 * TPB], pd = p4[j + 3 * TPB];
        int4   ga = g4[j], gb = g4[j + TPB], gc = g4[j + 2 * TPB], gd = g4[j + 3 * TPB];
        for (int g = 1; g < groups; ++g) {
            j = base + g * 4 * TPB;
            float4 qa = p4[j], qb = p4[j + TPB], qc = p4[j + 2 * TPB], qd = p4[j + 3 * TPB];
            int4   ra = g4[j], rb = g4[j + TPB], rc = g4[j + 2 * TPB], rd = g4[j + 3 * TPB];
            PROCESS16(pa, pb, pc, pd, ga, gb, gc, gd);
            pa = qa; pb = qb; pc = qc; pd = qd;
            ga = ra; gb = rb; gc = rc; gd = rd;
        }
        PROCESS16(pa, pb, pc, pd, ga, gb, gc, gd);
        it = groups * 4;
    }
    for (; it < iters; ++it) {                        // remainder groups (0 at n=2^25)
        int i = base + it * TPB;
        float4 p = p4[i]; int4 g = g4[i];
        bump(h, tid, p.x, g.x); bump(h, tid, p.y, g.y);
        bump(h, tid, p.z, g.z); bump(h, tid, p.w, g.w);
    }
    {   // non-uniform extra vec4s beyond the uniform region (none at n=2^25)
        int i = gsz * iters + blockIdx.x * TPB + tid;
        if (i < nvec) {
            float4 p = p4[i]; int4 g = g4[i];
            bump(h, tid, p.x, g.x); bump(h, tid, p.y, g.y);
            bump(h, tid, p.z, g.z); bump(h, tid, p.w, g.w);
        }
    }

    // scalar tail (n % 4) — empty at n=2^25; tid 0's own column, race-free
    if (blockIdx.x == 0 && tid == 0) {
        for (int k = nvec << 2; k < n; ++k)
            h[bin_of(pred[k]) * TPB] += 1u + ((unsigned int)(gt[k] != 0) << 16);
    }

    __syncthreads();
    // fold: bin r sums its 256 u32 cells; staggered start ((j+tid)%256).
    // ONE global atomic per (block,bin): 256*101 total.
    if (tid < NBINS) {
        const unsigned int* row = &hist[tid][0];
        unsigned long long cnt = 0ull, pos = 0ull;
        for (int j = 0; j < TPB; ++j) {
            int jj = j + tid; if (jj >= TPB) jj -= TPB;
            unsigned int v = row[jj];
            cnt += v & 0xffffu;
            pos += v >> 16;
        }
        if (cnt | pos) atomicAdd(&ws[tid], (pos << 32) | cnt);
        __threadfence();   // adds device-visible before the ticket
    }
    __syncthreads();
    if (tid == 0) {
        unsigned long long t = atomicAdd(&ws[NBINS], 1ull);
        is_last = (t == (unsigned long long)(gridDim.x - 1)) ? 1 : 0;
    }
    __syncthreads();

    if (is_last) {
        if (tid < NBINS) {   // atomic-read: bypass stale L1, post-fence values
            unsigned long long hv = atomicAdd(&ws[tid], 0ull);
            fpos[tid] = (unsigned int)(hv >> 32);
            fall[tid] = (unsigned int)(hv & 0xffffffffull);
        }
        __syncthreads();
        if (tid < N_THRESH) {
            out[tid] = (float)((double)tid * 0.01);
            unsigned long long tp = 0, pp = 0, ngt = 0;
            for (int c = tid + 1; c <= N_THRESH; ++c) { tp += fpos[c]; pp += fall[c]; }
            for (int c = 0; c <= N_THRESH; ++c) ngt += fpos[c];
            long long uni = (long long)(pp + ngt - tp);   // TP + FP + FN
            double iou = (uni > 0) ? (double)tp / (double)uni : 0.0;
            out[N_THRESH + tid] = (float)iou;
        }
    }
}

// ---------------------------------------------------------------------------
extern "C" void kernel_launch(void* const* d_in, const int* in_sizes, int n_in,
                              void* d_out, int out_size, void* d_ws, size_t ws_size,
                              hipStream_t stream) {
    const float* pred = (const float*)d_in[0];
    const int*   gt   = (const int*)d_in[1];
    float* out = (float*)d_out;
    unsigned long long* ws = (unsigned long long*)d_ws;
    int n = in_sizes[0];

    zero_ws_kernel<<<1, 128, 0, stream>>>(ws);
    hist_kernel<<<GRID, TPB, 0, stream>>>(pred, gt, ws, out, n);
}

// Round 8
// 287.924 us; speedup vs baseline: 1.2239x; 1.0248x over previous
//
#include <hip/hip_runtime.h>

#define N_THRESH 100
#define NBINS 101
#define NCOL 102       // col 101 = "single element, no partner" slot
#define TPB 256        // 4 waves/block; LDS ~83 KB -> 1 block/CU
#define GRID 256       // one block per CU (R6 grid-stride beat R7 contiguous)

// ---------------------------------------------------------------------------
// Kernel 0: zero accumulator bins + completion ticket (d_ws poisoned 0xAA).
// ---------------------------------------------------------------------------
__global__ void zero_ws_kernel(unsigned long long* __restrict__ ws) {
    int i = threadIdx.x;
    if (i < NBINS + 1) ws[i] = 0ull;   // [0..100] = (pos<<32|cnt), [101] = ticket
}

// ---------------------------------------------------------------------------
// Branch-free exact bin: cnt = searchsorted(thresholds, v, side='left'),
// thresholds[k] = float32(double(k)*0.01) (bit-exact np.arange match).
// Verified absmax=0 across five runs — do not touch.
// ---------------------------------------------------------------------------
__device__ __forceinline__ int bin_of(float v) {
    int e = (int)(v * 100.0f);
    e = e < 0 ? 0 : (e > 99 ? 99 : e);
    double ed = (double)e * 0.01;
    float t0 = (float)ed;           // threshold e
    float t1 = (float)(ed + 0.01);  // threshold e+1 (==1.0f when e==99)
    int c = e + (t0 < v ? 1 : 0) + (t1 < v ? 1 : 0);
    return c > N_THRESH ? N_THRESH : c;
}

// ---------------------------------------------------------------------------
// MEASURED MODEL (R0..R7, 5 schemes): scattered LDS = ~1 lane-op/cyc/CU
// (atomic = 2). Per-element LDS floor = ~2.1 cyc/lane-elem = ~114us.
// THIS VERSION: ONE u64 atomic per PAIR of elements into a joint
// cells[bin_a][bin_b] matrix -> 1 scattered lane-request / 2 elements.
// u64 fields: npairs[0:20) | posA[20:40) | posB[40:60).
// Overflow-safe for ANY data: pairs/block = 65,536 < 2^20.
// Margins (both histograms) recovered by STRUCTURED row/col scans (no scatter).
// ---------------------------------------------------------------------------
__device__ __forceinline__ void bump_pair(unsigned long long* __restrict__ c,
                                          float va, int ga, float vb, int gb) {
    int a = bin_of(va), b = bin_of(vb);
    unsigned long long contrib = 1ull
        | ((unsigned long long)(ga != 0) << 20)
        | ((unsigned long long)(gb != 0) << 40);
    atomicAdd(&c[a * NCOL + b], contrib);   // ds_add_u64, fire-and-forget
}

#define PROCESS16(PA, PB, PC, PD, GA, GB, GC, GD) do {                 \
    bump_pair(cells, (PA).x, (GA).x, (PA).y, (GA).y);                  \
    bump_pair(cells, (PA).z, (GA).z, (PA).w, (GA).w);                  \
    bump_pair(cells, (PB).x, (GB).x, (PB).y, (GB).y);                  \
    bump_pair(cells, (PB).z, (GB).z, (PB).w, (GB).w);                  \
    bump_pair(cells, (PC).x, (GC).x, (PC).y, (GC).y);                  \
    bump_pair(cells, (PC).z, (GC).z, (PC).w, (GC).w);                  \
    bump_pair(cells, (PD).x, (GD).x, (PD).y, (GD).y);                  \
    bump_pair(cells, (PD).z, (GD).z, (PD).w, (GD).w);                  \
} while (0)

// ---------------------------------------------------------------------------
// Kernel 1: joint-pair histogram + margins + (last block) finalize via ticket.
// ---------------------------------------------------------------------------
__global__ __launch_bounds__(TPB) void hist_kernel(
        const float* __restrict__ pred,
        const int* __restrict__ gt,
        unsigned long long* __restrict__ ws,
        float* __restrict__ out,
        int n) {
    __shared__ unsigned long long cells[NBINS * NCOL];   // 82,416 B
    __shared__ unsigned int fpos[NBINS], fall[NBINS];
    __shared__ int is_last;

    const int tid = threadIdx.x;

    {   // zero as dwords: 101*102*2 = 20,604 dwords
        unsigned int* z = (unsigned int*)cells;
        for (int i = tid; i < NBINS * NCOL * 2; i += TPB) z[i] = 0u;
    }
    __syncthreads();

    const int nvec = n >> 2;
    const float4* __restrict__ p4 = (const float4*)pred;
    const int4*   __restrict__ g4 = (const int4*)gt;
    const int gsz = gridDim.x * blockDim.x;           // 65,536
    const int i0  = blockIdx.x * blockDim.x + tid;
    const int iters  = nvec / gsz;                    // 128 at n=2^25 (uniform)
    const int groups = iters >> 2;                    // 32

    int it = 0;
    if (groups > 0) {
        // software-pipelined: group g's 8x16B loads issue before group g-1's
        // atomic chain; atomics are fire-and-forget (no lgkmcnt dependency).
        int j = i0;
        float4 pa = p4[j], pb = p4[j + gsz], pc = p4[j + 2 * gsz], pd = p4[j + 3 * gsz];
        int4   ga = g4[j], gb = g4[j + gsz], gc = g4[j + 2 * gsz], gd = g4[j + 3 * gsz];
        for (int g = 1; g < groups; ++g) {
            j = i0 + g * 4 * gsz;
            float4 qa = p4[j], qb = p4[j + gsz], qc = p4[j + 2 * gsz], qd = p4[j + 3 * gsz];
            int4   ra = g4[j], rb = g4[j + gsz], rc = g4[j + 2 * gsz], rd = g4[j + 3 * gsz];
            PROCESS16(pa, pb, pc, pd, ga, gb, gc, gd);
            pa = qa; pb = qb; pc = qc; pd = qd;
            ga = ra; gb = rb; gc = rc; gd = rd;
        }
        PROCESS16(pa, pb, pc, pd, ga, gb, gc, gd);
        it = groups * 4;
    }
    for (; it < iters; ++it) {                        // remainder (0 at n=2^25)
        int i = i0 + it * gsz;
        float4 p = p4[i]; int4 g = g4[i];
        bump_pair(cells, p.x, g.x, p.y, g.y);
        bump_pair(cells, p.z, g.z, p.w, g.w);
    }
    {   // non-uniform extra vec4 (first nvec%gsz threads; none at n=2^25)
        int i = i0 + iters * gsz;
        if (i < nvec) {
            float4 p = p4[i]; int4 g = g4[i];
            bump_pair(cells, p.x, g.x, p.y, g.y);
            bump_pair(cells, p.z, g.z, p.w, g.w);
        }
    }

    // scalar tail (n % 4) — empty at n=2^25; singles go to col 101 (posB=0,
    // partner never counted: col 101 is excluded from the column scan)
    if (blockIdx.x == 0 && tid == 0) {
        for (int k = nvec << 2; k < n; ++k) {
            unsigned long long contrib = 1ull
                | ((unsigned long long)(gt[k] != 0) << 20);
            cells[bin_of(pred[k]) * NCOL + NBINS] += contrib;   // race-free
        }
    }

    __syncthreads();
    // margins via STRUCTURED scans (no scatter):
    //   row scan  (a=tid): npairs -> first-elem count, posA -> first-elem pos
    //   col scan  (b=tid): npairs -> second-elem count, posB -> second-elem pos
    if (tid < NBINS) {
        unsigned long long cnt = 0ull, pos = 0ull;
        const unsigned long long* row = &cells[tid * NCOL];
        for (int j = 0; j < NCOL; ++j) {             // row a = tid, cols 0..101
            unsigned long long v = row[j];
            cnt += v & 0xFFFFFull;                   // npairs
            pos += (v >> 20) & 0xFFFFFull;           // posA
        }
        for (int i = 0; i < NBINS; ++i) {            // col b = tid, rows 0..100
            unsigned long long v = cells[i * NCOL + tid];
            cnt += v & 0xFFFFFull;                   // npairs (second elem)
            pos += (v >> 40) & 0xFFFFFull;           // posB
        }
        if (cnt | pos) atomicAdd(&ws[tid], (pos << 32) | cnt);
        __threadfence();   // adds device-visible before the ticket
    }
    __syncthreads();
    if (tid == 0) {
        unsigned long long t = atomicAdd(&ws[NBINS], 1ull);
        is_last = (t == (unsigned long long)(gridDim.x - 1)) ? 1 : 0;
    }
    __syncthreads();

    if (is_last) {
        if (tid < NBINS) {   // atomic-read: bypass stale L1, post-fence values
            unsigned long long hv = atomicAdd(&ws[tid], 0ull);
            fpos[tid] = (unsigned int)(hv >> 32);
            fall[tid] = (unsigned int)(hv & 0xffffffffull);
        }
        __syncthreads();
        if (tid < N_THRESH) {
            out[tid] = (float)((double)tid * 0.01);
            unsigned long long tp = 0, pp = 0, ngt = 0;
            for (int c = tid + 1; c <= N_THRESH; ++c) { tp += fpos[c]; pp += fall[c]; }
            for (int c = 0; c <= N_THRESH; ++c) ngt += fpos[c];
            long long uni = (long long)(pp + ngt - tp);   // TP + FP + FN
            double iou = (uni > 0) ? (double)tp / (double)uni : 0.0;
            out[N_THRESH + tid] = (float)iou;
        }
    }
}

// ---------------------------------------------------------------------------
extern "C" void kernel_launch(void* const* d_in, const int* in_sizes, int n_in,
                              void* d_out, int out_size, void* d_ws, size_t ws_size,
                              hipStream_t stream) {
    const float* pred = (const float*)d_in[0];
    const int*   gt   = (const int*)d_in[1];
    float* out = (float*)d_out;
    unsigned long long* ws = (unsigned long long*)d_ws;
    int n = in_sizes[0];

    zero_ws_kernel<<<1, 128, 0, stream>>>(ws);
    hist_kernel<<<GRID, TPB, 0, stream>>>(pred, gt, ws, out, n);
}

// Round 9
// 286.873 us; speedup vs baseline: 1.2284x; 1.0037x over previous
//
#include <hip/hip_runtime.h>

#define N_THRESH 100
#define NBINS 101
#define NB2 202        // (bin*2 + gt) composite index, 0..201
#define TPB 256        // 4 waves/block; LDS 163,216+ B -> 1 block/CU
#define GRID 256       // one block per CU (R6 grid-stride > R7 contiguous)

// ---------------------------------------------------------------------------
// Kernel 0: zero accumulator bins + completion ticket (d_ws poisoned 0xAA).
// ---------------------------------------------------------------------------
__global__ void zero_ws_kernel(unsigned long long* __restrict__ ws) {
    int i = threadIdx.x;
    if (i < NBINS + 1) ws[i] = 0ull;   // [0..100] = (pos<<32|cnt), [101] = ticket
}

// ---------------------------------------------------------------------------
// Branch-free exact bin: cnt = searchsorted(thresholds, v, side='left'),
// thresholds[k] = float32(double(k)*0.01) (bit-exact np.arange match).
// Verified absmax=0 across six runs — do not touch.
// ---------------------------------------------------------------------------
__device__ __forceinline__ int bin_of(float v) {
    int e = (int)(v * 100.0f);
    e = e < 0 ? 0 : (e > 99 ? 99 : e);
    double ed = (double)e * 0.01;
    float t0 = (float)ed;           // threshold e
    float t1 = (float)(ed + 0.01);  // threshold e+1 (==1.0f when e==99)
    int c = e + (t0 < v ? 1 : 0) + (t1 < v ? 1 : 0);
    return c > N_THRESH ? N_THRESH : c;
}

// ---------------------------------------------------------------------------
// MEASURED MODEL (6 experiments, R0..R8): scattered LDS costs ~1 cyc per
// LANE-DWORD TOUCHED per CU (atomic RMW = 2 touches; u64 = 2 dwords).
// All prior schemes = 2 touches/element = ~262K cyc/CU = ~114us floor.
// THIS VERSION: 1 u32 atomic per PAIR, gt bits folded into the INDEX:
//   cells[(bin_a*2+ga)][(bin_b*2+gb)] += 1   -> 1 touch per element.
// Count-only u32: overflow-free for any n (< 2^32 pairs/block), no flushes.
// Margins recovered by STRUCTURED row/col scans (no scatter).
// ---------------------------------------------------------------------------
__device__ __forceinline__ void bump_pair(unsigned int* __restrict__ c,
                                          float va, int ga, float vb, int gb) {
    int ra = bin_of(va) * 2 + (ga != 0);
    int cb = bin_of(vb) * 2 + (gb != 0);
    atomicAdd(&c[ra * NB2 + cb], 1u);   // ds_add_u32, fire-and-forget
}

#define PROCESS16(PA, PB, PC, PD, GA, GB, GC, GD) do {                 \
    bump_pair(cells, (PA).x, (GA).x, (PA).y, (GA).y);                  \
    bump_pair(cells, (PA).z, (GA).z, (PA).w, (GA).w);                  \
    bump_pair(cells, (PB).x, (GB).x, (PB).y, (GB).y);                  \
    bump_pair(cells, (PB).z, (GB).z, (PB).w, (GB).w);                  \
    bump_pair(cells, (PC).x, (GC).x, (PC).y, (GC).y);                  \
    bump_pair(cells, (PC).z, (GC).z, (PC).w, (GC).w);                  \
    bump_pair(cells, (PD).x, (GD).x, (PD).y, (GD).y);                  \
    bump_pair(cells, (PD).z, (GD).z, (PD).w, (GD).w);                  \
} while (0)

// ---------------------------------------------------------------------------
// Kernel 1: joint (bin,gt)^2 count histogram + margins + last-block finalize.
// ---------------------------------------------------------------------------
__global__ __launch_bounds__(TPB) void hist_kernel(
        const float* __restrict__ pred,
        const int* __restrict__ gt,
        unsigned long long* __restrict__ ws,
        float* __restrict__ out,
        int n) {
    __shared__ unsigned int cells[NB2 * NB2];   // 163,216 B (fits 160 KiB CU)
    __shared__ int is_last;

    const int tid = threadIdx.x;

    for (int i = tid; i < NB2 * NB2; i += TPB) cells[i] = 0u;  // stride-256: conflict-free
    __syncthreads();

    const int nvec = n >> 2;
    const float4* __restrict__ p4 = (const float4*)pred;
    const int4*   __restrict__ g4 = (const int4*)gt;
    const int gsz = gridDim.x * blockDim.x;           // 65,536
    const int i0  = blockIdx.x * blockDim.x + tid;
    const int iters  = nvec / gsz;                    // 128 at n=2^25 (uniform)
    const int groups = iters >> 2;                    // 32

    int it = 0;
    if (groups > 0) {
        // load-ahead pipeline: group g's 8x16B loads issue before group g-1's
        // atomics (fire-and-forget: no lgkmcnt chain, pure DS throughput).
        int j = i0;
        float4 pa = p4[j], pb = p4[j + gsz], pc = p4[j + 2 * gsz], pd = p4[j + 3 * gsz];
        int4   ga = g4[j], gb = g4[j + gsz], gc = g4[j + 2 * gsz], gd = g4[j + 3 * gsz];
        for (int g = 1; g < groups; ++g) {
            j = i0 + g * 4 * gsz;
            float4 qa = p4[j], qb = p4[j + gsz], qc = p4[j + 2 * gsz], qd = p4[j + 3 * gsz];
            int4   ra = g4[j], rb = g4[j + gsz], rc = g4[j + 2 * gsz], rd = g4[j + 3 * gsz];
            PROCESS16(pa, pb, pc, pd, ga, gb, gc, gd);
            pa = qa; pb = qb; pc = qc; pd = qd;
            ga = ra; gb = rb; gc = rc; gd = rd;
        }
        PROCESS16(pa, pb, pc, pd, ga, gb, gc, gd);
        it = groups * 4;
    }
    for (; it < iters; ++it) {                        // remainder (0 at n=2^25)
        int i = i0 + it * gsz;
        float4 p = p4[i]; int4 g = g4[i];
        bump_pair(cells, p.x, g.x, p.y, g.y);
        bump_pair(cells, p.z, g.z, p.w, g.w);
    }
    {   // non-uniform extra vec4 (first nvec%gsz threads; none at n=2^25)
        int i = i0 + iters * gsz;
        if (i < nvec) {
            float4 p = p4[i]; int4 g = g4[i];
            bump_pair(cells, p.x, g.x, p.y, g.y);
            bump_pair(cells, p.z, g.z, p.w, g.w);
        }
    }

    // scalar tail (n % 4, <=3 elems) — straight to global ws, bypasses cells
    if (blockIdx.x == 0 && tid == 0) {
        for (int k = nvec << 2; k < n; ++k) {
            unsigned long long s =
                ((unsigned long long)(gt[k] != 0) << 32) | 1ull;
            atomicAdd(&ws[bin_of(pred[k])], s);
        }
    }

    __syncthreads();
    // STRUCTURED margins: thread t (t<202) sums row t and column t.
    //   rowsum(2a+ga) = #first-elems  with bin a, gt ga
    //   colsum(2b+gb) = #second-elems with bin b, gt gb
    unsigned int rsum = 0, csum = 0;
    if (tid < NB2) {
        const unsigned int* row = &cells[tid * NB2];
        for (int j = 0; j < NB2; ++j) rsum += row[j];          // ~4-way bank, tiny
        for (int i = 0; i < NB2; ++i) csum += cells[i * NB2 + tid]; // 2 lanes/bank
    }
    __syncthreads();           // all reads of cells done
    if (tid < NB2) {           // reuse cells[] as reduction scratch
        cells[tid]       = rsum;
        cells[NB2 + tid] = csum;
    }
    __syncthreads();
    if (tid < NBINS) {
        unsigned long long cnt =
            (unsigned long long)cells[2 * tid] + cells[2 * tid + 1]
          + cells[NB2 + 2 * tid] + cells[NB2 + 2 * tid + 1];
        unsigned long long pos =
            (unsigned long long)cells[2 * tid + 1] + cells[NB2 + 2 * tid + 1];
        if (cnt | pos) atomicAdd(&ws[tid], (pos << 32) | cnt);
        __threadfence();       // adds device-visible before the ticket
    }
    __syncthreads();
    if (tid == 0) {
        unsigned long long t = atomicAdd(&ws[NBINS], 1ull);
        is_last = (t == (unsigned long long)(gridDim.x - 1)) ? 1 : 0;
    }
    __syncthreads();

    if (is_last) {
        if (tid < NBINS) {     // atomic-read: bypass stale L1, post-fence values
            unsigned long long hv = atomicAdd(&ws[tid], 0ull);
            cells[tid]         = (unsigned int)(hv >> 32);          // pos
            cells[NB2 + tid]   = (unsigned int)(hv & 0xffffffffull); // all
        }
        __syncthreads();
        if (tid < N_THRESH) {
            out[tid] = (float)((double)tid * 0.01);
            unsigned long long tp = 0, pp = 0, ngt = 0;
            for (int c = tid + 1; c <= N_THRESH; ++c) {
                tp += cells[c]; pp += cells[NB2 + c];
            }
            for (int c = 0; c <= N_THRESH; ++c) ngt += cells[c];
            long long uni = (long long)(pp + ngt - tp);   // TP + FP + FN
            double iou = (uni > 0) ? (double)tp / (double)uni : 0.0;
            out[N_THRESH + tid] = (float)iou;
        }
    }
}

// ---------------------------------------------------------------------------
extern "C" void kernel_launch(void* const* d_in, const int* in_sizes, int n_in,
                              void* d_out, int out_size, void* d_ws, size_t ws_size,
                              hipStream_t stream) {
    const float* pred = (const float*)d_in[0];
    const int*   gt   = (const int*)d_in[1];
    float* out = (float*)d_out;
    unsigned long long* ws = (unsigned long long*)d_ws;
    int n = in_sizes[0];

    zero_ws_kernel<<<1, 128, 0, stream>>>(ws);
    hist_kernel<<<GRID, TPB, 0, stream>>>(pred, gt, ws, out, n);
}